// Round 5
// baseline (14436.555 us; speedup 1.0000x reference)
//
#include <hip/hip_runtime.h>
#include <math.h>

#define Bsz 16384
#define Msz 512
#define Nsz 2048

typedef _Float16 half8 __attribute__((ext_vector_type(8)));
typedef _Float16 half4 __attribute__((ext_vector_type(4)));
typedef _Float16 half2v __attribute__((ext_vector_type(2)));
typedef float floatx16 __attribute__((ext_vector_type(16)));
typedef unsigned int uint;

struct HL { _Float16 h, l; };
__device__ __forceinline__ HL split1(float x) {
    HL r;
    r.h = (_Float16)x;
    r.l = (_Float16)(x - (float)r.h);   // exact residual (two-term split)
    return r;
}
__device__ __forceinline__ uint packHL(float x) {
    HL s = split1(x);
    return (uint)__builtin_bit_cast(unsigned short, s.h)
         | ((uint)__builtin_bit_cast(unsigned short, s.l) << 16);
}
__device__ __forceinline__ float unpackHL(uint w) {
    half2v p = __builtin_bit_cast(half2v, w);
    return (float)p.x + (float)p.y;
}

// async global->LDS, 16B per lane. LDS dest = wave-uniform base + lane*16.
__device__ __forceinline__ void gl_lds16(const _Float16* g, _Float16* l) {
    __builtin_amdgcn_global_load_lds(
        (const __attribute__((address_space(1))) unsigned int*)g,
        (__attribute__((address_space(3))) unsigned int*)l, 16, 0, 0);
}

// raw barrier: no compiler-inserted vmcnt(0) drain (unlike __syncthreads).
#define BAR()  asm volatile("s_barrier" ::: "memory")

// fragment-permuted layout (32x32x16 MFMA), lane-linear (bank-conflict-free):
// element (r,k) of [R][K] at frag(r>>5, k>>4)*512
//                          + ((k>>3)&1)*256 + (r&31)*8 + (k&7)      [halves]
// => lane l's half8 operand (r=l&31, k=(l>>5)*8 ..+7) sits at frag*512 + l*8:
//    a wave's ds_read_b128 covers 1KB contiguous -> all 32 banks, conflict-free.

// zero 19*Bsz floats (t2 slabs 1..9 + na2 slabs 0..9, contiguous)
__global__ __launch_bounds__(256) void zero_kernel(float4* __restrict__ p) {
    p[blockIdx.x * 256 + threadIdx.x] = make_float4(0.f, 0.f, 0.f, 0.f);
}

// iter-0: v = batch -> single f16 permuted plane; t2s[0][b] = sum(v^2) (fp32).
__global__ __launch_bounds__(256) void init_kernel(const float* __restrict__ batch,
        _Float16* __restrict__ vh, float* __restrict__ t2) {
    const int wave = threadIdx.x >> 6;
    const int lane = threadIdx.x & 63;
    const int b = (blockIdx.x << 2) + wave;
    const float* row = batch + (size_t)b * Msz + lane * 8;
    float4 a = *(const float4*)row;
    float4 c = *(const float4*)(row + 4);
    half8 h;
    h[0] = (_Float16)a.x; h[1] = (_Float16)a.y;
    h[2] = (_Float16)a.z; h[3] = (_Float16)a.w;
    h[4] = (_Float16)c.x; h[5] = (_Float16)c.y;
    h[6] = (_Float16)c.z; h[7] = (_Float16)c.w;
    // m = lane*8: frag col = lane>>1, (k>>3)&1 = lane&1, k&7 = 0
    const size_t off = ((size_t)(b >> 5) * 32 + (lane >> 1)) * 512
                     + ((size_t)(lane & 1) << 8) + ((b & 31) << 3);
    *(half8*)(vh + off) = h;
    float s = a.x*a.x + a.y*a.y + a.z*a.z + a.w*a.w
            + c.x*c.x + c.y*c.y + c.z*c.z + c.w*c.w;
#pragma unroll
    for (int off2 = 32; off2 > 0; off2 >>= 1) s += __shfl_down(s, off2);
    if (lane == 0) t2[b] = s;
}

// One-time: D [M][N] fp32 -> Dperm hi/lo  (gemm2 B: r=m, k=n, K=2048)
//                        and Dtperm hi/lo (gemm1 B: r=n, k=m, K=512)
__global__ __launch_bounds__(256) void convD_kernel(const float* __restrict__ D,
        _Float16* __restrict__ Dph, _Float16* __restrict__ Dpl,
        _Float16* __restrict__ Dtph, _Float16* __restrict__ Dtpl) {
    __shared__ float T[64][65];
    const int t = threadIdx.x;
    const int tx = t & 15, ty = t >> 4;
    const int n0 = blockIdx.x << 6, m0 = blockIdx.y << 6;
#pragma unroll
    for (int q = 0; q < 4; ++q) {
        const int mr = m0 + (ty << 2) + q;
        const int nc = n0 + (tx << 2);
        float4 d = *(const float4*)(D + (size_t)mr * Nsz + nc);
        half4 h, l;
        HL s0 = split1(d.x), s1 = split1(d.y), s2 = split1(d.z), s3 = split1(d.w);
        h[0] = s0.h; l[0] = s0.l; h[1] = s1.h; l[1] = s1.l;
        h[2] = s2.h; l[2] = s2.l; h[3] = s3.h; l[3] = s3.l;
        // r=mr, k=nc (nc multiple of 4 -> 4 halves contiguous in k&7 group)
        const size_t o2 = ((size_t)(mr >> 5) * 128 + (nc >> 4)) * 512
                        + (((size_t)(nc >> 3) & 1) << 8) + ((mr & 31) << 3) + (nc & 7);
        *(half4*)(Dph + o2) = h;
        *(half4*)(Dpl + o2) = l;
        T[(tx << 2) + 0][(ty << 2) + q] = d.x;
        T[(tx << 2) + 1][(ty << 2) + q] = d.y;
        T[(tx << 2) + 2][(ty << 2) + q] = d.z;
        T[(tx << 2) + 3][(ty << 2) + q] = d.w;
    }
    __syncthreads();
#pragma unroll
    for (int q = 0; q < 4; ++q) {
        const int nr = n0 + (ty << 2) + q;
        const int mc = m0 + (tx << 2);
        float4 d = make_float4(T[(ty << 2) + q][tx << 2],
                               T[(ty << 2) + q][(tx << 2) + 1],
                               T[(ty << 2) + q][(tx << 2) + 2],
                               T[(ty << 2) + q][(tx << 2) + 3]);
        half4 h, l;
        HL s0 = split1(d.x), s1 = split1(d.y), s2 = split1(d.z), s3 = split1(d.w);
        h[0] = s0.h; l[0] = s0.l; h[1] = s1.h; l[1] = s1.l;
        h[2] = s2.h; l[2] = s2.l; h[3] = s3.h; l[3] = s3.l;
        // r=nr, k=mc
        const size_t o1 = ((size_t)(nr >> 5) * 32 + (mc >> 4)) * 512
                        + (((size_t)(mc >> 3) & 1) << 8) + ((nr & 31) << 3) + (mc & 7);
        *(half4*)(Dtph + o1) = h;
        *(half4*)(Dtpl + o1) = l;
    }
}

// gemm1: alpha = relu((first?0:alpha) + beta*(v@D) - t[b]); fused na2 atomic.
// 256x256 tile, grid 512, 8 waves (2x4), per-wave 128x64 out (acc[4][2]).
// 48KB single-buffer LDS, R2-proven stage->drain->compute (2 blocks/CU TLP
// hides the drain). 32 MFMA per wave per barrier-pair (2x amortization vs
// 256x128); staged traffic 384 MB/dispatch (was 512). Lane-linear layout.
__global__ __launch_bounds__(512, 4) void gemm1_kernel(
        const _Float16* __restrict__ Av,
        const _Float16* __restrict__ Bth, const _Float16* __restrict__ Btl,
        const float* __restrict__ t2,
        uint* __restrict__ alphaP,
        float* __restrict__ na2,
        const float* __restrict__ beta_p, const float* __restrict__ gamma_p,
        int first, int last) {
    __shared__ _Float16 lds[24576];   // 48KB: A 16 frags | Bh 16 | Bl 16 (512h each)

    const int tid = threadIdx.x;
    const int wave = tid >> 6, lane = tid & 63;
    const int wy = wave >> 2, wx = wave & 3;     // 2x4 wave grid
    const int ln = lane & 31, lh = lane >> 5;
    const int bid = blockIdx.x;
    const int b0 = (bid & 63) << 8;              // 64 row-tiles of 256
    const int n0 = (bid >> 6) << 8;              // 8 col-tiles of 256
    const int R0 = b0 >> 5, C0 = n0 >> 5;

    floatx16 acc[4][2] = {};

    // staging: 48 frags/chunk (A 0-15 | Bh 16-31 | Bl 32-47), 6 per wave.
    // frag f: plane p=f>>4, q=f&15, subtile t=q>>1, ktile kt=q&1.
    const _Float16* pb[6];
#pragma unroll
    for (int e = 0; e < 6; ++e) {
        const int f = wave * 6 + e;
        const int p = f >> 4, q = f & 15, t = q >> 1, kt = q & 1;
        const _Float16* base = (p == 0) ? Av : (p == 1) ? Bth : Btl;
        const int T0 = (p == 0) ? R0 : C0;
        pb[e] = base + ((size_t)(T0 + t) * 32) * 512 + (size_t)kt * 512 + lane * 8;
    }
    const int f0 = wave * 6;

    const int ro = lane << 3;            // lane-linear fragment read offset (halves)

    for (int c = 0; c < 16; ++c) {
        __syncthreads();                 // previous chunk's frag reads done
#pragma unroll
        for (int e = 0; e < 6; ++e)
            gl_lds16(pb[e] + (size_t)c * 1024, lds + ((f0 + e) << 9));
        __builtin_amdgcn_s_waitcnt(0);   // drain this wave's DMA
        __syncthreads();                 // all frags staged

#pragma unroll
        for (int ks = 0; ks < 2; ++ks) {
            half8 fa[4], fbh[2], fbl[2];
#pragma unroll
            for (int i = 0; i < 4; ++i)
                fa[i]  = *(const half8*)(lds + ((((4 * wy + i) << 1) + ks) << 9) + ro);
#pragma unroll
            for (int j = 0; j < 2; ++j) {
                const int sb = (((2 * wx + j) << 1) + ks) << 9;
                fbh[j] = *(const half8*)(lds + 8192 + sb + ro);
                fbl[j] = *(const half8*)(lds + 16384 + sb + ro);
            }
#pragma unroll
            for (int j = 0; j < 2; ++j)
#pragma unroll
                for (int i = 0; i < 4; ++i) {
                    acc[i][j] = __builtin_amdgcn_mfma_f32_32x32x16_f16(fa[i], fbh[j], acc[i][j], 0, 0, 0);
                    acc[i][j] = __builtin_amdgcn_mfma_f32_32x32x16_f16(fa[i], fbl[j], acc[i][j], 0, 0, 0);
                }
        }
    }

    const float beta = beta_p[0];
    const float tc = gamma_p[0] * 0.044194173824159216f;   // gamma / sqrt(512)
#pragma unroll
    for (int i = 0; i < 4; ++i) {
#pragma unroll
        for (int reg = 0; reg < 16; ++reg) {
            const int rr = (reg & 3) + 8 * (reg >> 2) + 4 * lh;   // 0..31
            const int b = b0 + wy * 128 + i * 32 + rr;
            const float tb2 = tc * sqrtf(t2[b]);
            uint* arow = alphaP + (size_t)b * Nsz + n0 + wx * 64 + ln;
            float s = 0.f;
#pragma unroll
            for (int j = 0; j < 2; ++j) {
                float z = first ? 0.f : unpackHL(arow[j * 32]);
                float val = fmaxf(fmaf(beta, acc[i][j][reg], z) - tb2, 0.f);
                if (last) ((float*)arow)[j * 32] = val;   // final fp32, same 4-B slot
                else      arow[j * 32] = packHL(val);
                s = fmaf(val, val, s);
            }
            s += __shfl_down(s, 16, 32);
            s += __shfl_down(s, 8, 32);
            s += __shfl_down(s, 4, 32);
            s += __shfl_down(s, 2, 32);
            s += __shfl_down(s, 1, 32);
            if (ln == 0) atomicAdd(&na2[b], s);
        }
    }
}

// gemm2: v = y - beta*(alpha@D^T) + beta/512*sqrt(na2[b])*v_old; fused t2 atomic.
// 256x128 tile, 8 waves, grid 256 (1 block/CU). T3+T4: raw barriers, counted
// vmcnt(6), lgkmcnt(0) before closing barrier commits A ds_writes. UNCHANGED (R4).
__global__ __launch_bounds__(512, 2) void gemm2_kernel(
        const uint* __restrict__ alphaP,
        const _Float16* __restrict__ Bh, const _Float16* __restrict__ Bl,
        const float* __restrict__ na2,
        const float* __restrict__ y,
        _Float16* __restrict__ vh,
        float* __restrict__ t2,
        const float* __restrict__ beta_p) {
    __shared__ _Float16 lds[32768];   // 64KB: 2 x (A 16 frags | Bh 8 | Bl 8)

    const int tid = threadIdx.x;
    const int wave = tid >> 6, lane = tid & 63;
    const int wy = wave >> 1, wx = wave & 1;
    const int ln = lane & 31, lh = lane >> 5;
    const int bid = blockIdx.x;
    const int b0 = (bid & 63) << 8;              // 64 row-tiles of 256
    const int m0 = (bid >> 6) << 7;              // 4 col-tiles of 128
    const int C0 = m0 >> 5;

    floatx16 acc[2][2] = {};

    // A staging: thread (srow, skq) covers one ktile-half of one row (16 words)
    const int srow = tid >> 1;                   // 0..255
    const int skq  = (tid & 1) << 4;
    const uint* apP = alphaP + (size_t)(b0 + srow) * Nsz + skq;
    // lane-linear frag layout: k&15 in 0..7 -> +0, 8..15 -> +256
    const int awo = ((((srow >> 5) << 1) + (skq >> 4)) << 9) + ((srow & 31) << 3);

    // B staging via gl_lds: waves 0-3 -> Bh ctile (wave&3); waves 4-7 -> Bl
    const _Float16* gB = ((wave < 4) ? Bh : Bl)
                       + ((size_t)(C0 + (wave & 3)) * 128) * 512 + lane * 8;
    const int fB = 16 + ((wave < 4) ? 0 : 8) + (wave & 3) * 2;

    const int ro = lane << 3;

    uint4 a0, a1, a2, a3;
    auto loadA = [&](int c) {
        const uint* nx = apP + c * 32;
        a0 = *(const uint4*)(nx);
        a1 = *(const uint4*)(nx + 4);
        a2 = *(const uint4*)(nx + 8);
        a3 = *(const uint4*)(nx + 12);
    };
    auto writeA = [&](int d) {      // extract hi (low16s) and ds_write in frag format
        uint4 ha, hb;
        ha.x = __builtin_amdgcn_perm(a0.y, a0.x, 0x05040100u);
        ha.y = __builtin_amdgcn_perm(a0.w, a0.z, 0x05040100u);
        ha.z = __builtin_amdgcn_perm(a1.y, a1.x, 0x05040100u);
        ha.w = __builtin_amdgcn_perm(a1.w, a1.z, 0x05040100u);
        hb.x = __builtin_amdgcn_perm(a2.y, a2.x, 0x05040100u);
        hb.y = __builtin_amdgcn_perm(a2.w, a2.z, 0x05040100u);
        hb.z = __builtin_amdgcn_perm(a3.y, a3.x, 0x05040100u);
        hb.w = __builtin_amdgcn_perm(a3.w, a3.z, 0x05040100u);
        _Float16* aw = lds + d * 16384 + awo;
        *(uint4*)aw = ha;
        *(uint4*)(aw + 256) = hb;
    };
    auto stageB = [&](int c, int d) {
        _Float16* lB = lds + d * 16384;
#pragma unroll
        for (int kt = 0; kt < 2; ++kt)
            gl_lds16(gB + (((size_t)2 * c + kt) << 9), lB + ((fB + kt) << 9));
    };

    // prologue: buf0 complete; buf1 B in flight + A written; regs hold A(2)
    loadA(0);
    writeA(0);
    stageB(0, 0);
    loadA(1);
    writeA(1);            // auto vmcnt wait drains loadA(1) (and older stageB(0))
    stageB(1, 1);
    loadA(2);
    asm volatile("s_waitcnt vmcnt(6) lgkmcnt(0)" ::: "memory");
    BAR();

    for (int c = 0; c < 64; ++c) {
        const _Float16* lb = lds + (c & 1) * 16384;
        __builtin_amdgcn_s_setprio(1);
#pragma unroll
        for (int ks = 0; ks < 2; ++ks) {
            half8 fa[2], fbh[2], fbl[2];
#pragma unroll
            for (int i = 0; i < 2; ++i) {
                const int sa = (((wy * 2 + i) << 1) + ks) << 9;
                const int sb = (((wx * 2 + i) << 1) + ks) << 9;
                fa[i]  = *(const half8*)(lb + sa + ro);
                fbh[i] = *(const half8*)(lb + 8192 + sb + ro);
                fbl[i] = *(const half8*)(lb + 12288 + sb + ro);
            }
#pragma unroll
            for (int j = 0; j < 2; ++j)
#pragma unroll
                for (int i = 0; i < 2; ++i) {
                    acc[i][j] = __builtin_amdgcn_mfma_f32_32x32x16_f16(fa[i], fbh[j], acc[i][j], 0, 0, 0);
                    acc[i][j] = __builtin_amdgcn_mfma_f32_32x32x16_f16(fa[i], fbl[j], acc[i][j], 0, 0, 0);
                }
        }
        __builtin_amdgcn_s_setprio(0);
        if (c == 63) break;
        BAR();                           // readers of buf[c&1] done
        if (c < 61) {
            stageB(c + 2, c & 1);        // B(c+2) flies across the barrier
            writeA(c & 1);               // A(c+2); auto-wait drains loadA(c+2)+stageB(c+1)
            loadA(c + 3);                // A regs for next chunk's writeA
            asm volatile("s_waitcnt vmcnt(6) lgkmcnt(0)" ::: "memory");
        } else if (c == 61) {
            stageB(63, 1);
            writeA(1);                   // A(63)
            asm volatile("s_waitcnt vmcnt(2) lgkmcnt(0)" ::: "memory");
        } else {                         // c == 62: drain stage(63)
            asm volatile("s_waitcnt vmcnt(0) lgkmcnt(0)" ::: "memory");
        }
        BAR();                           // buf[(c+1)&1] published
    }

    const float beta = beta_p[0];
#pragma unroll
    for (int i = 0; i < 2; ++i) {
#pragma unroll
        for (int reg = 0; reg < 16; ++reg) {
            const int rr = (reg & 3) + 8 * (reg >> 2) + 4 * lh;
            const int b = b0 + wy * 64 + i * 32 + rr;
            const float cb = beta * (1.0f / 512.0f) * sqrtf(na2[b]);
            float s = 0.f;
#pragma unroll
            for (int j = 0; j < 2; ++j) {
                const int m = m0 + wx * 64 + j * 32 + ln;
                const size_t po = ((size_t)(b >> 5) * 32 + (m >> 4)) * 512
                                + (((size_t)(m >> 3) & 1) << 8) + ((b & 31) << 3) + (m & 7);
                const size_t yi = (size_t)b * Msz + m;
                float vold = (float)vh[po];
                float val = y[yi] - beta * acc[i][j][reg] + cb * vold;
                vh[po] = (_Float16)val;
                s = fmaf(val, val, s);
            }
            s += __shfl_down(s, 16, 32);
            s += __shfl_down(s, 8, 32);
            s += __shfl_down(s, 4, 32);
            s += __shfl_down(s, 2, 32);
            s += __shfl_down(s, 1, 32);
            if (ln == 0) atomicAdd(&t2[b], s);
        }
    }
}

extern "C" void kernel_launch(void* const* d_in, const int* in_sizes, int n_in,
                              void* d_out, int out_size, void* d_ws, size_t ws_size,
                              hipStream_t stream) {
    (void)in_sizes; (void)n_in; (void)out_size; (void)ws_size;
    const float* batch   = (const float*)d_in[0];   // [B, M]
    const float* D       = (const float*)d_in[1];   // [M, N]
    const float* gamma_p = (const float*)d_in[2];   // scalar
    const float* beta_p  = (const float*)d_in[3];   // scalar

    uint* alphaP = (uint*)d_out;    // packed hi/lo per element (plain layout); fp32 after final iter

    // workspace (~27 MB)
    _Float16* vh   = (_Float16*)d_ws;               // [B*M] permuted, single plane
    _Float16* Dph  = vh + (size_t)Bsz * Msz;        // [M*N] permuted (gemm2 B)
    _Float16* Dpl  = Dph + (size_t)Msz * Nsz;
    _Float16* Dtph = Dpl + (size_t)Msz * Nsz;       // [N*M] permuted (gemm1 B)
    _Float16* Dtpl = Dtph + (size_t)Msz * Nsz;
    float*    t2s  = (float*)(Dtpl + (size_t)Msz * Nsz);   // [10][Bsz] sum v^2
    float*    na2s = t2s + 10 * Bsz;                        // [10][Bsz] sum alpha^2

    // zero t2 slabs 1..9 + na2 slabs 0..9 (contiguous 19*Bsz floats)
    zero_kernel<<<19 * Bsz / 1024, 256, 0, stream>>>((float4*)(t2s + Bsz));
    convD_kernel<<<dim3(Nsz / 64, Msz / 64), 256, 0, stream>>>(D, Dph, Dpl, Dtph, Dtpl);
    init_kernel<<<Bsz / 4, 256, 0, stream>>>(batch, vh, t2s);   // writes t2 slab 0

    for (int it = 0; it < 10; ++it) {
        gemm1_kernel<<<512, 512, 0, stream>>>(vh, Dtph, Dtpl,
                                              t2s + (size_t)it * Bsz,
                                              alphaP,
                                              na2s + (size_t)it * Bsz,
                                              beta_p, gamma_p,
                                              it == 0 ? 1 : 0, it == 9 ? 1 : 0);
        if (it < 9) {   // last iteration's new_v is unused by the reference output
            gemm2_kernel<<<256, 512, 0, stream>>>(alphaP, Dph, Dpl,
                                                  na2s + (size_t)it * Bsz,
                                                  batch, vh,
                                                  t2s + (size_t)(it + 1) * Bsz,
                                                  beta_p);
        }
    }
}

// Round 6
// 1785.184 us; speedup vs baseline: 8.0869x; 8.0869x over previous
//
#include <hip/hip_runtime.h>
#include <math.h>

#define Bsz 16384
#define Msz 512
#define Nsz 2048

typedef _Float16 half8 __attribute__((ext_vector_type(8)));
typedef _Float16 half4 __attribute__((ext_vector_type(4)));
typedef _Float16 half2v __attribute__((ext_vector_type(2)));
typedef float floatx16 __attribute__((ext_vector_type(16)));
typedef unsigned int uint;

struct HL { _Float16 h, l; };
__device__ __forceinline__ HL split1(float x) {
    HL r;
    r.h = (_Float16)x;
    r.l = (_Float16)(x - (float)r.h);   // exact residual (two-term split)
    return r;
}
__device__ __forceinline__ uint packHL(float x) {
    HL s = split1(x);
    return (uint)__builtin_bit_cast(unsigned short, s.h)
         | ((uint)__builtin_bit_cast(unsigned short, s.l) << 16);
}
__device__ __forceinline__ float unpackHL(uint w) {
    half2v p = __builtin_bit_cast(half2v, w);
    return (float)p.x + (float)p.y;
}

// async global->LDS, 16B per lane. LDS dest = wave-uniform base + lane*16.
__device__ __forceinline__ void gl_lds16(const _Float16* g, _Float16* l) {
    __builtin_amdgcn_global_load_lds(
        (const __attribute__((address_space(1))) unsigned int*)g,
        (__attribute__((address_space(3))) unsigned int*)l, 16, 0, 0);
}

// raw barrier: no compiler-inserted vmcnt(0) drain (unlike __syncthreads).
#define BAR()  asm volatile("s_barrier" ::: "memory")

// fragment-permuted layout (32x32x16 MFMA), lane-linear (bank-conflict-free):
// element (r,k) of [R][K] at frag(r>>5, k>>4)*512
//                          + ((k>>3)&1)*256 + (r&31)*8 + (k&7)      [halves]
// => lane l's half8 operand (r=l&31, k=(l>>5)*8 ..+7) sits at frag*512 + l*8:
//    a wave's ds_read_b128 covers 1KB contiguous -> all 32 banks, conflict-free.

// zero 19*Bsz floats (t2 slabs 1..9 + na2 slabs 0..9, contiguous)
__global__ __launch_bounds__(256) void zero_kernel(float4* __restrict__ p) {
    p[blockIdx.x * 256 + threadIdx.x] = make_float4(0.f, 0.f, 0.f, 0.f);
}

// iter-0: v = batch -> single f16 permuted plane; t2s[0][b] = sum(v^2) (fp32).
__global__ __launch_bounds__(256) void init_kernel(const float* __restrict__ batch,
        _Float16* __restrict__ vh, float* __restrict__ t2) {
    const int wave = threadIdx.x >> 6;
    const int lane = threadIdx.x & 63;
    const int b = (blockIdx.x << 2) + wave;
    const float* row = batch + (size_t)b * Msz + lane * 8;
    float4 a = *(const float4*)row;
    float4 c = *(const float4*)(row + 4);
    half8 h;
    h[0] = (_Float16)a.x; h[1] = (_Float16)a.y;
    h[2] = (_Float16)a.z; h[3] = (_Float16)a.w;
    h[4] = (_Float16)c.x; h[5] = (_Float16)c.y;
    h[6] = (_Float16)c.z; h[7] = (_Float16)c.w;
    // m = lane*8: frag col = lane>>1, (k>>3)&1 = lane&1, k&7 = 0
    const size_t off = ((size_t)(b >> 5) * 32 + (lane >> 1)) * 512
                     + ((size_t)(lane & 1) << 8) + ((b & 31) << 3);
    *(half8*)(vh + off) = h;
    float s = a.x*a.x + a.y*a.y + a.z*a.z + a.w*a.w
            + c.x*c.x + c.y*c.y + c.z*c.z + c.w*c.w;
#pragma unroll
    for (int off2 = 32; off2 > 0; off2 >>= 1) s += __shfl_down(s, off2);
    if (lane == 0) t2[b] = s;
}

// One-time: D [M][N] fp32 -> Dph  (gemm2 B: r=m, k=n, K=2048) single f16 plane
//                        and Dtph (gemm1 B: r=n, k=m, K=512)  single f16 plane
__global__ __launch_bounds__(256) void convD_kernel(const float* __restrict__ D,
        _Float16* __restrict__ Dph, _Float16* __restrict__ Dtph) {
    __shared__ float T[64][65];
    const int t = threadIdx.x;
    const int tx = t & 15, ty = t >> 4;
    const int n0 = blockIdx.x << 6, m0 = blockIdx.y << 6;
#pragma unroll
    for (int q = 0; q < 4; ++q) {
        const int mr = m0 + (ty << 2) + q;
        const int nc = n0 + (tx << 2);
        float4 d = *(const float4*)(D + (size_t)mr * Nsz + nc);
        half4 h;
        h[0] = (_Float16)d.x; h[1] = (_Float16)d.y;
        h[2] = (_Float16)d.z; h[3] = (_Float16)d.w;
        // r=mr, k=nc (nc multiple of 4 -> 4 halves contiguous in k&7 group)
        const size_t o2 = ((size_t)(mr >> 5) * 128 + (nc >> 4)) * 512
                        + (((size_t)(nc >> 3) & 1) << 8) + ((mr & 31) << 3) + (nc & 7);
        *(half4*)(Dph + o2) = h;
        T[(tx << 2) + 0][(ty << 2) + q] = d.x;
        T[(tx << 2) + 1][(ty << 2) + q] = d.y;
        T[(tx << 2) + 2][(ty << 2) + q] = d.z;
        T[(tx << 2) + 3][(ty << 2) + q] = d.w;
    }
    __syncthreads();
#pragma unroll
    for (int q = 0; q < 4; ++q) {
        const int nr = n0 + (ty << 2) + q;
        const int mc = m0 + (tx << 2);
        float4 d = make_float4(T[(ty << 2) + q][tx << 2],
                               T[(ty << 2) + q][(tx << 2) + 1],
                               T[(ty << 2) + q][(tx << 2) + 2],
                               T[(ty << 2) + q][(tx << 2) + 3]);
        half4 h;
        h[0] = (_Float16)d.x; h[1] = (_Float16)d.y;
        h[2] = (_Float16)d.z; h[3] = (_Float16)d.w;
        // r=nr, k=mc
        const size_t o1 = ((size_t)(nr >> 5) * 32 + (mc >> 4)) * 512
                        + (((size_t)(mc >> 3) & 1) << 8) + ((nr & 31) << 3) + (mc & 7);
        *(half4*)(Dtph + o1) = h;
    }
}

// gemm1: alpha = relu((first?0:alpha) + beta*(v@D) - t[b]); fused na2 atomic.
// Single-plane f16 D. 256x128 tile, 8 waves (4x2), acc[2][2] (no spill),
// BK=64 (8 chunks), 48KB single-buffer (A 32 frags | Bh 16 frags),
// R3-proven stage->drain->compute (cross-block TLP hides the drain).
__global__ __launch_bounds__(512, 4) void gemm1_kernel(
        const _Float16* __restrict__ Av,
        const _Float16* __restrict__ Bth,
        const float* __restrict__ t2,
        uint* __restrict__ alphaP,
        float* __restrict__ na2,
        const float* __restrict__ beta_p, const float* __restrict__ gamma_p,
        int first, int last) {
    __shared__ _Float16 lds[24576];   // 48KB: A frags 0..31 | Bh frags 32..47

    const int tid = threadIdx.x;
    const int wave = tid >> 6, lane = tid & 63;
    const int wy = wave >> 1, wx = wave & 1;     // 4x2 wave grid
    const int ln = lane & 31, lh = lane >> 5;
    const int bid = blockIdx.x;
    const int b0 = (bid & 63) << 8;              // 64 row-tiles of 256
    const int n0 = (bid >> 6) << 7;              // 16 col-tiles of 128
    const int R0 = b0 >> 5, C0 = n0 >> 5;

    floatx16 acc[2][2] = {};

    // staging: 48 frags/chunk (A 0-31 | Bh 32-47), 6 per wave.
    // A frag f: subtile t=f>>2, ktile kt=f&3.  B frag 32+q: t=q>>2, kt=q&3.
    const _Float16* pb[6];
#pragma unroll
    for (int e = 0; e < 6; ++e) {
        const int f = wave * 6 + e;
        const bool isB = f >= 32;
        const int q = isB ? f - 32 : f;
        const int t = q >> 2, kt = q & 3;
        const _Float16* base = isB ? Bth : Av;
        const int T0 = isB ? C0 : R0;
        pb[e] = base + ((size_t)(T0 + t) * 32) * 512 + (size_t)kt * 512 + lane * 8;
    }
    const int f0 = wave * 6;

    const int ro = lane << 3;            // lane-linear fragment read offset (halves)

    for (int c = 0; c < 8; ++c) {        // BK=64: 4 ktiles per chunk
        __syncthreads();                 // previous chunk's frag reads done
#pragma unroll
        for (int e = 0; e < 6; ++e)
            gl_lds16(pb[e] + (size_t)c * 2048, lds + ((f0 + e) << 9));
        __builtin_amdgcn_s_waitcnt(0);   // drain this wave's DMA
        __syncthreads();                 // all frags staged

#pragma unroll
        for (int ks = 0; ks < 4; ++ks) {
            half8 fa[2], fb[2];
#pragma unroll
            for (int i = 0; i < 2; ++i) {
                fa[i] = *(const half8*)(lds + ((((wy * 2 + i) << 2) + ks) << 9) + ro);
                fb[i] = *(const half8*)(lds + 16384 + ((((wx * 2 + i) << 2) + ks) << 9) + ro);
            }
#pragma unroll
            for (int j = 0; j < 2; ++j)
#pragma unroll
                for (int i = 0; i < 2; ++i)
                    acc[i][j] = __builtin_amdgcn_mfma_f32_32x32x16_f16(fa[i], fb[j], acc[i][j], 0, 0, 0);
        }
    }

    const float beta = beta_p[0];
    const float tc = gamma_p[0] * 0.044194173824159216f;   // gamma / sqrt(512)
#pragma unroll
    for (int i = 0; i < 2; ++i) {
#pragma unroll
        for (int reg = 0; reg < 16; ++reg) {
            const int rr = (reg & 3) + 8 * (reg >> 2) + 4 * lh;   // 0..31
            const int b = b0 + wy * 64 + i * 32 + rr;
            const float tb2 = tc * sqrtf(t2[b]);
            uint* arow = alphaP + (size_t)b * Nsz + n0 + wx * 64 + ln;
            float s = 0.f;
#pragma unroll
            for (int j = 0; j < 2; ++j) {
                float z = first ? 0.f : unpackHL(arow[j * 32]);
                float val = fmaxf(fmaf(beta, acc[i][j][reg], z) - tb2, 0.f);
                if (last) ((float*)arow)[j * 32] = val;   // final fp32, same 4-B slot
                else      arow[j * 32] = packHL(val);
                s = fmaf(val, val, s);
            }
            s += __shfl_down(s, 16, 32);
            s += __shfl_down(s, 8, 32);
            s += __shfl_down(s, 4, 32);
            s += __shfl_down(s, 2, 32);
            s += __shfl_down(s, 1, 32);
            if (ln == 0) atomicAdd(&na2[b], s);
        }
    }
}

// gemm2: v = y - beta*(alpha@D^T) + beta/512*sqrt(na2[b])*v_old; fused t2 atomic.
// Single-plane f16 D. 256x128 tile, 8 waves, grid 256 (1 block/CU).
// T3+T4: raw barriers, counted vmcnt (never 0 mid-loop), 48KB double-buffer
// (2 x (A 16 frags | Bh 8)). A = alpha_hi regs (load c+3, write c+2).
__global__ __launch_bounds__(512, 2) void gemm2_kernel(
        const uint* __restrict__ alphaP,
        const _Float16* __restrict__ Bh,
        const float* __restrict__ na2,
        const float* __restrict__ y,
        _Float16* __restrict__ vh,
        float* __restrict__ t2,
        const float* __restrict__ beta_p) {
    __shared__ _Float16 lds[24576];   // 48KB: 2 x (A 16 frags | Bh 8)

    const int tid = threadIdx.x;
    const int wave = tid >> 6, lane = tid & 63;
    const int wy = wave >> 1, wx = wave & 1;
    const int ln = lane & 31, lh = lane >> 5;
    const int bid = blockIdx.x;
    const int b0 = (bid & 63) << 8;              // 64 row-tiles of 256
    const int m0 = (bid >> 6) << 7;              // 4 col-tiles of 128
    const int C0 = m0 >> 5;

    floatx16 acc[2][2] = {};

    // A staging: thread (srow, skq) covers one ktile-half of one row (16 words)
    const int srow = tid >> 1;                   // 0..255
    const int skq  = (tid & 1) << 4;
    const uint* apP = alphaP + (size_t)(b0 + srow) * Nsz + skq;
    // lane-linear frag layout: k&15 in 0..7 -> +0, 8..15 -> +256
    const int awo = ((((srow >> 5) << 1) + (skq >> 4)) << 9) + ((srow & 31) << 3);

    // B staging via gl_lds: wave w stages frag 16+w (subtile w>>1, ktile w&1)
    const _Float16* gB = Bh + ((size_t)(C0 + (wave >> 1)) * 128) * 512
                       + (size_t)(wave & 1) * 512 + lane * 8;
    const int fB = 16 + wave;

    const int ro = lane << 3;

    uint4 a0, a1, a2, a3;
    auto loadA = [&](int c) {
        const uint* nx = apP + c * 32;
        a0 = *(const uint4*)(nx);
        a1 = *(const uint4*)(nx + 4);
        a2 = *(const uint4*)(nx + 8);
        a3 = *(const uint4*)(nx + 12);
    };
    auto writeA = [&](int d) {      // extract hi (low16s) and ds_write in frag format
        uint4 ha, hb;
        ha.x = __builtin_amdgcn_perm(a0.y, a0.x, 0x05040100u);
        ha.y = __builtin_amdgcn_perm(a0.w, a0.z, 0x05040100u);
        ha.z = __builtin_amdgcn_perm(a1.y, a1.x, 0x05040100u);
        ha.w = __builtin_amdgcn_perm(a1.w, a1.z, 0x05040100u);
        hb.x = __builtin_amdgcn_perm(a2.y, a2.x, 0x05040100u);
        hb.y = __builtin_amdgcn_perm(a2.w, a2.z, 0x05040100u);
        hb.z = __builtin_amdgcn_perm(a3.y, a3.x, 0x05040100u);
        hb.w = __builtin_amdgcn_perm(a3.w, a3.z, 0x05040100u);
        _Float16* aw = lds + d * 12288 + awo;
        *(uint4*)aw = ha;
        *(uint4*)(aw + 256) = hb;
    };
    auto stageB = [&](int c, int d) {
        gl_lds16(gB + (size_t)c * 1024, lds + d * 12288 + (fB << 9));
    };

    // prologue: buf0 complete; buf1 B in flight + A written; regs hold A(2)
    loadA(0);
    writeA(0);
    stageB(0, 0);
    loadA(1);
    writeA(1);            // implicit vmcnt wait drains loadA(1) (and stageB(0))
    stageB(1, 1);
    loadA(2);
    asm volatile("s_waitcnt vmcnt(5) lgkmcnt(0)" ::: "memory");
    BAR();

    for (int c = 0; c < 64; ++c) {
        const _Float16* lb = lds + (c & 1) * 12288;
        __builtin_amdgcn_s_setprio(1);
#pragma unroll
        for (int ks = 0; ks < 2; ++ks) {
            half8 fa[2], fb[2];
#pragma unroll
            for (int i = 0; i < 2; ++i) {
                fa[i] = *(const half8*)(lb + ((((wy * 2 + i) << 1) + ks) << 9) + ro);
                fb[i] = *(const half8*)(lb + 8192 + ((((wx * 2 + i) << 1) + ks) << 9) + ro);
            }
#pragma unroll
            for (int j = 0; j < 2; ++j)
#pragma unroll
                for (int i = 0; i < 2; ++i)
                    acc[i][j] = __builtin_amdgcn_mfma_f32_32x32x16_f16(fa[i], fb[j], acc[i][j], 0, 0, 0);
        }
        __builtin_amdgcn_s_setprio(0);
        if (c == 63) break;
        BAR();                           // readers of buf[c&1] done
        if (c < 62) {
            stageB(c + 2, c & 1);        // B(c+2) flies across barriers
            writeA(c & 1);               // A(c+2); implicit wait: B(c+1)+A(c+2) done
            if (c < 61) loadA(c + 3);    // A regs for next chunk's writeA
            asm volatile("s_waitcnt vmcnt(5) lgkmcnt(0)" ::: "memory");
        } else {                         // c == 62: drain stageB(63)
            asm volatile("s_waitcnt vmcnt(0) lgkmcnt(0)" ::: "memory");
        }
        BAR();                           // buf[(c+1)&1] published
    }

    const float beta = beta_p[0];
#pragma unroll
    for (int i = 0; i < 2; ++i) {
#pragma unroll
        for (int reg = 0; reg < 16; ++reg) {
            const int rr = (reg & 3) + 8 * (reg >> 2) + 4 * lh;
            const int b = b0 + wy * 64 + i * 32 + rr;
            const float cb = beta * (1.0f / 512.0f) * sqrtf(na2[b]);
            float s = 0.f;
#pragma unroll
            for (int j = 0; j < 2; ++j) {
                const int m = m0 + wx * 64 + j * 32 + ln;
                const size_t po = ((size_t)(b >> 5) * 32 + (m >> 4)) * 512
                                + (((size_t)(m >> 3) & 1) << 8) + ((b & 31) << 3) + (m & 7);
                const size_t yi = (size_t)b * Msz + m;
                float vold = (float)vh[po];
                float val = y[yi] - beta * acc[i][j][reg] + cb * vold;
                vh[po] = (_Float16)val;
                s = fmaf(val, val, s);
            }
            s += __shfl_down(s, 16, 32);
            s += __shfl_down(s, 8, 32);
            s += __shfl_down(s, 4, 32);
            s += __shfl_down(s, 2, 32);
            s += __shfl_down(s, 1, 32);
            if (ln == 0) atomicAdd(&t2[b], s);
        }
    }
}

extern "C" void kernel_launch(void* const* d_in, const int* in_sizes, int n_in,
                              void* d_out, int out_size, void* d_ws, size_t ws_size,
                              hipStream_t stream) {
    (void)in_sizes; (void)n_in; (void)out_size; (void)ws_size;
    const float* batch   = (const float*)d_in[0];   // [B, M]
    const float* D       = (const float*)d_in[1];   // [M, N]
    const float* gamma_p = (const float*)d_in[2];   // scalar
    const float* beta_p  = (const float*)d_in[3];   // scalar

    uint* alphaP = (uint*)d_out;    // packed hi/lo per element (plain layout); fp32 after final iter

    // workspace (~20 MB)
    _Float16* vh   = (_Float16*)d_ws;               // [B*M] permuted, single plane
    _Float16* Dph  = vh + (size_t)Bsz * Msz;        // [M*N] permuted (gemm2 B), f16
    _Float16* Dtph = Dph + (size_t)Msz * Nsz;       // [N*M] permuted (gemm1 B), f16
    float*    t2s  = (float*)(Dtph + (size_t)Msz * Nsz);   // [10][Bsz] sum v^2
    float*    na2s = t2s + 10 * Bsz;                        // [10][Bsz] sum alpha^2

    // zero t2 slabs 1..9 + na2 slabs 0..9 (contiguous 19*Bsz floats)
    zero_kernel<<<19 * Bsz / 1024, 256, 0, stream>>>((float4*)(t2s + Bsz));
    convD_kernel<<<dim3(Nsz / 64, Msz / 64), 256, 0, stream>>>(D, Dph, Dtph);
    init_kernel<<<Bsz / 4, 256, 0, stream>>>(batch, vh, t2s);   // writes t2 slab 0

    for (int it = 0; it < 10; ++it) {
        gemm1_kernel<<<1024, 512, 0, stream>>>(vh, Dtph,
                                               t2s + (size_t)it * Bsz,
                                               alphaP,
                                               na2s + (size_t)it * Bsz,
                                               beta_p, gamma_p,
                                               it == 0 ? 1 : 0, it == 9 ? 1 : 0);
        if (it < 9) {   // last iteration's new_v is unused by the reference output
            gemm2_kernel<<<256, 512, 0, stream>>>(alphaP, Dph,
                                                  na2s + (size_t)it * Bsz,
                                                  batch, vh,
                                                  t2s + (size_t)(it + 1) * Bsz,
                                                  beta_p);
        }
    }
}

// Round 8
// 1743.900 us; speedup vs baseline: 8.2783x; 1.0237x over previous
//
#include <hip/hip_runtime.h>
#include <math.h>

#define Bsz 16384
#define Msz 512
#define Nsz 2048

typedef _Float16 half8 __attribute__((ext_vector_type(8)));
typedef _Float16 half4 __attribute__((ext_vector_type(4)));
typedef _Float16 half2v __attribute__((ext_vector_type(2)));
typedef float floatx16 __attribute__((ext_vector_type(16)));
typedef unsigned int uint;

struct HL { _Float16 h, l; };
__device__ __forceinline__ HL split1(float x) {
    HL r;
    r.h = (_Float16)x;
    r.l = (_Float16)(x - (float)r.h);   // exact residual (two-term split)
    return r;
}
__device__ __forceinline__ uint packHL(float x) {
    HL s = split1(x);
    return (uint)__builtin_bit_cast(unsigned short, s.h)
         | ((uint)__builtin_bit_cast(unsigned short, s.l) << 16);
}
__device__ __forceinline__ float unpackHL(uint w) {
    half2v p = __builtin_bit_cast(half2v, w);
    return (float)p.x + (float)p.y;
}

// async global->LDS, 16B per lane. LDS dest = wave-uniform base + lane*16.
__device__ __forceinline__ void gl_lds16(const _Float16* g, _Float16* l) {
    __builtin_amdgcn_global_load_lds(
        (const __attribute__((address_space(1))) unsigned int*)g,
        (__attribute__((address_space(3))) unsigned int*)l, 16, 0, 0);
}

// raw barrier: no compiler-inserted vmcnt(0) drain (unlike __syncthreads).
#define BAR()  asm volatile("s_barrier" ::: "memory")

// fragment-permuted layout (32x32x16 MFMA), lane-linear (bank-conflict-free):
// element (r,k) of [R][K] at frag((r>>5)*(K/16) + (k>>4))*512
//                          + ((k>>3)&1)*256 + (r&31)*8 + (k&7)      [halves]
// => lane l's half8 operand (r=l&31, k=(l>>5)*8 ..+7) sits at frag*512 + l*8:
//    a wave's ds_read_b128 covers 1KB contiguous -> all 32 banks, conflict-free.
// NOTE frag-row stride = K/16: 32 for K=512 planes (Av, Dtph, vh), 128 for
// K=2048 plane (Dph). R7's bug was using 32 for Dph.

// zero 19*Bsz floats (t2 slabs 1..9 + na2 slabs 0..9, contiguous)
__global__ __launch_bounds__(256) void zero_kernel(float4* __restrict__ p) {
    p[blockIdx.x * 256 + threadIdx.x] = make_float4(0.f, 0.f, 0.f, 0.f);
}

// iter-0: v = batch -> single f16 permuted plane; t2s[0][b] = sum(v^2) (fp32).
__global__ __launch_bounds__(256) void init_kernel(const float* __restrict__ batch,
        _Float16* __restrict__ vh, float* __restrict__ t2) {
    const int wave = threadIdx.x >> 6;
    const int lane = threadIdx.x & 63;
    const int b = (blockIdx.x << 2) + wave;
    const float* row = batch + (size_t)b * Msz + lane * 8;
    float4 a = *(const float4*)row;
    float4 c = *(const float4*)(row + 4);
    half8 h;
    h[0] = (_Float16)a.x; h[1] = (_Float16)a.y;
    h[2] = (_Float16)a.z; h[3] = (_Float16)a.w;
    h[4] = (_Float16)c.x; h[5] = (_Float16)c.y;
    h[6] = (_Float16)c.z; h[7] = (_Float16)c.w;
    // m = lane*8: frag col = lane>>1, (k>>3)&1 = lane&1, k&7 = 0
    const size_t off = ((size_t)(b >> 5) * 32 + (lane >> 1)) * 512
                     + ((size_t)(lane & 1) << 8) + ((b & 31) << 3);
    *(half8*)(vh + off) = h;
    float s = a.x*a.x + a.y*a.y + a.z*a.z + a.w*a.w
            + c.x*c.x + c.y*c.y + c.z*c.z + c.w*c.w;
#pragma unroll
    for (int off2 = 32; off2 > 0; off2 >>= 1) s += __shfl_down(s, off2);
    if (lane == 0) t2[b] = s;
}

// One-time: D [M][N] fp32 -> Dph  (gemm2 B: r=m, k=n, K=2048) single f16 plane
//                        and Dtph (gemm1 B: r=n, k=m, K=512)  single f16 plane
__global__ __launch_bounds__(256) void convD_kernel(const float* __restrict__ D,
        _Float16* __restrict__ Dph, _Float16* __restrict__ Dtph) {
    __shared__ float T[64][65];
    const int t = threadIdx.x;
    const int tx = t & 15, ty = t >> 4;
    const int n0 = blockIdx.x << 6, m0 = blockIdx.y << 6;
#pragma unroll
    for (int q = 0; q < 4; ++q) {
        const int mr = m0 + (ty << 2) + q;
        const int nc = n0 + (tx << 2);
        float4 d = *(const float4*)(D + (size_t)mr * Nsz + nc);
        half4 h;
        h[0] = (_Float16)d.x; h[1] = (_Float16)d.y;
        h[2] = (_Float16)d.z; h[3] = (_Float16)d.w;
        // r=mr, k=nc: frag-row stride 128 (K=2048)
        const size_t o2 = ((size_t)(mr >> 5) * 128 + (nc >> 4)) * 512
                        + (((size_t)(nc >> 3) & 1) << 8) + ((mr & 31) << 3) + (nc & 7);
        *(half4*)(Dph + o2) = h;
        T[(tx << 2) + 0][(ty << 2) + q] = d.x;
        T[(tx << 2) + 1][(ty << 2) + q] = d.y;
        T[(tx << 2) + 2][(ty << 2) + q] = d.z;
        T[(tx << 2) + 3][(ty << 2) + q] = d.w;
    }
    __syncthreads();
#pragma unroll
    for (int q = 0; q < 4; ++q) {
        const int nr = n0 + (ty << 2) + q;
        const int mc = m0 + (tx << 2);
        float4 d = make_float4(T[(ty << 2) + q][tx << 2],
                               T[(ty << 2) + q][(tx << 2) + 1],
                               T[(ty << 2) + q][(tx << 2) + 2],
                               T[(ty << 2) + q][(tx << 2) + 3]);
        half4 h;
        h[0] = (_Float16)d.x; h[1] = (_Float16)d.y;
        h[2] = (_Float16)d.z; h[3] = (_Float16)d.w;
        // r=nr, k=mc: frag-row stride 32 (K=512)
        const size_t o1 = ((size_t)(nr >> 5) * 32 + (mc >> 4)) * 512
                        + (((size_t)(mc >> 3) & 1) << 8) + ((nr & 31) << 3) + (mc & 7);
        *(half4*)(Dtph + o1) = h;
    }
}

// gemm1: alpha = relu((first?0:alpha) + beta*(v@D) - t[b]); fused na2 atomic.
// 128x128 tile, 4 waves (2x2), 16KB single-buffer LDS, BK=32 (16 chunks),
// stage->drain->compute. Grid 2048 -> 4 resident blocks/CU: cross-block TLP
// hides the drain (the only mechanism that has moved this kernel).
__global__ __launch_bounds__(256, 4) void gemm1_kernel(
        const _Float16* __restrict__ Av,
        const _Float16* __restrict__ Bth,
        const float* __restrict__ t2,
        uint* __restrict__ alphaP,
        float* __restrict__ na2,
        const float* __restrict__ beta_p, const float* __restrict__ gamma_p,
        int first, int last) {
    __shared__ _Float16 lds[8192];    // 16KB: A frags 0..7 | B frags 8..15

    const int tid = threadIdx.x;
    const int wave = tid >> 6, lane = tid & 63;
    const int wy = wave >> 1, wx = wave & 1;     // 2x2 wave grid
    const int ln = lane & 31, lh = lane >> 5;
    const int bid = blockIdx.x;
    const int b0 = (bid & 127) << 7;             // 128 row-tiles of 128
    const int n0 = (bid >> 7) << 7;              // 16 col-tiles of 128
    const int R0 = b0 >> 5, C0 = n0 >> 5;

    floatx16 acc[2][2] = {};

    // staging: 16 frags/chunk, 4 per wave. frag f<8: A subtile f>>1, ktile f&1;
    // f>=8: B subtile (f-8)>>1, ktile (f-8)&1. Both planes K=512 -> stride 32.
    const _Float16* pb[4];
#pragma unroll
    for (int e = 0; e < 4; ++e) {
        const int f = wave * 4 + e;
        const bool isB = f >= 8;
        const int q = isB ? f - 8 : f;
        const int t = q >> 1, kt = q & 1;
        const _Float16* base = isB ? Bth : Av;
        const int T0 = isB ? C0 : R0;
        pb[e] = base + ((size_t)(T0 + t) * 32) * 512 + (size_t)kt * 512 + lane * 8;
    }
    const int f0 = wave * 4;

    const int ro = lane << 3;            // lane-linear fragment read offset (halves)

    for (int c = 0; c < 16; ++c) {       // BK=32
        __syncthreads();                 // previous chunk's frag reads done
#pragma unroll
        for (int e = 0; e < 4; ++e)
            gl_lds16(pb[e] + (size_t)c * 1024, lds + ((f0 + e) << 9));
        __builtin_amdgcn_s_waitcnt(0);   // drain this wave's DMA
        __syncthreads();                 // all frags staged

#pragma unroll
        for (int ks = 0; ks < 2; ++ks) {
            half8 fa[2], fb[2];
#pragma unroll
            for (int i = 0; i < 2; ++i) {
                fa[i] = *(const half8*)(lds + ((((wy * 2 + i) << 1) + ks) << 9) + ro);
                fb[i] = *(const half8*)(lds + 4096 + ((((wx * 2 + i) << 1) + ks) << 9) + ro);
            }
#pragma unroll
            for (int j = 0; j < 2; ++j)
#pragma unroll
                for (int i = 0; i < 2; ++i)
                    acc[i][j] = __builtin_amdgcn_mfma_f32_32x32x16_f16(fa[i], fb[j], acc[i][j], 0, 0, 0);
        }
    }

    const float beta = beta_p[0];
    const float tc = gamma_p[0] * 0.044194173824159216f;   // gamma / sqrt(512)
#pragma unroll
    for (int i = 0; i < 2; ++i) {
#pragma unroll
        for (int reg = 0; reg < 16; ++reg) {
            const int rr = (reg & 3) + 8 * (reg >> 2) + 4 * lh;   // 0..31
            const int b = b0 + wy * 64 + i * 32 + rr;
            const float tb2 = tc * sqrtf(t2[b]);
            uint* arow = alphaP + (size_t)b * Nsz + n0 + wx * 64 + ln;
            float s = 0.f;
#pragma unroll
            for (int j = 0; j < 2; ++j) {
                float z = first ? 0.f : unpackHL(arow[j * 32]);
                float val = fmaxf(fmaf(beta, acc[i][j][reg], z) - tb2, 0.f);
                if (last) ((float*)arow)[j * 32] = val;   // final fp32, same 4-B slot
                else      arow[j * 32] = packHL(val);
                s = fmaf(val, val, s);
            }
            s += __shfl_down(s, 16, 32);
            s += __shfl_down(s, 8, 32);
            s += __shfl_down(s, 4, 32);
            s += __shfl_down(s, 2, 32);
            s += __shfl_down(s, 1, 32);
            if (ln == 0) atomicAdd(&na2[b], s);
        }
    }
}

// gemm2: v = y - beta*(alpha@D^T) + beta/512*sqrt(na2[b])*v_old; fused t2 atomic.
// 128x128 tile, 4 waves (2x2), grid 512 = 2 blocks/CU. Double-buffered 32KB,
// counted vmcnt (never 0 mid-loop), raw barriers. A = alpha_hi regs
// (load c+3, write c+2); B via gl_lds (2 frags/wave).
__global__ __launch_bounds__(256, 2) void gemm2_kernel(
        const uint* __restrict__ alphaP,
        const _Float16* __restrict__ Bh,
        const float* __restrict__ na2,
        const float* __restrict__ y,
        _Float16* __restrict__ vh,
        float* __restrict__ t2,
        const float* __restrict__ beta_p) {
    __shared__ _Float16 lds[16384];   // 32KB: 2 x (A frags 0..7 | B frags 8..15)

    const int tid = threadIdx.x;
    const int wave = tid >> 6, lane = tid & 63;
    const int wy = wave >> 1, wx = wave & 1;
    const int ln = lane & 31, lh = lane >> 5;
    const int bid = blockIdx.x;
    const int b0 = (bid & 127) << 7;             // 128 row-tiles of 128
    const int m0 = (bid >> 7) << 7;              // 4 col-tiles of 128
    const int C0 = m0 >> 5;

    floatx16 acc[2][2] = {};

    // A staging: thread (srow, skq) covers one ktile-half of one row (16 words)
    const int srow = tid >> 1;                   // 0..127
    const int skq  = (tid & 1) << 4;
    const uint* apP = alphaP + (size_t)(b0 + srow) * Nsz + skq;
    // lane-linear frag layout: k&15 in 0..7 -> +0, 8..15 -> +256
    const int awo = ((((srow >> 5) << 1) + (skq >> 4)) << 9) + ((srow & 31) << 3);

    // B staging via gl_lds: wave w stages B subtile C0+w, both ktiles.
    // Dph frag-row stride = K/16 = 128 (K=2048) — R7's bug was 32 here.
    const _Float16* gB = Bh + ((size_t)(C0 + wave) * 128) * 512 + lane * 8;
    const int fB = 8 + wave * 2;

    const int ro = lane << 3;

    uint4 a0, a1, a2, a3;
    auto loadA = [&](int c) {
        const uint* nx = apP + c * 32;
        a0 = *(const uint4*)(nx);
        a1 = *(const uint4*)(nx + 4);
        a2 = *(const uint4*)(nx + 8);
        a3 = *(const uint4*)(nx + 12);
    };
    auto writeA = [&](int d) {      // extract hi (low16s) and ds_write in frag format
        uint4 ha, hb;
        ha.x = __builtin_amdgcn_perm(a0.y, a0.x, 0x05040100u);
        ha.y = __builtin_amdgcn_perm(a0.w, a0.z, 0x05040100u);
        ha.z = __builtin_amdgcn_perm(a1.y, a1.x, 0x05040100u);
        ha.w = __builtin_amdgcn_perm(a1.w, a1.z, 0x05040100u);
        hb.x = __builtin_amdgcn_perm(a2.y, a2.x, 0x05040100u);
        hb.y = __builtin_amdgcn_perm(a2.w, a2.z, 0x05040100u);
        hb.z = __builtin_amdgcn_perm(a3.y, a3.x, 0x05040100u);
        hb.w = __builtin_amdgcn_perm(a3.w, a3.z, 0x05040100u);
        _Float16* aw = lds + d * 8192 + awo;
        *(uint4*)aw = ha;
        *(uint4*)(aw + 256) = hb;
    };
    auto stageB = [&](int c, int d) {
        _Float16* lB = lds + d * 8192;
#pragma unroll
        for (int kt = 0; kt < 2; ++kt)
            gl_lds16(gB + (size_t)kt * 512 + (size_t)c * 1024, lB + ((fB + kt) << 9));
    };

    // prologue: buf0 complete; buf1 B in flight + A written; regs hold A(2)
    loadA(0);
    writeA(0);
    stageB(0, 0);
    loadA(1);
    writeA(1);            // implicit vmcnt wait drains loadA(1) (and stageB(0))
    stageB(1, 1);
    loadA(2);
    asm volatile("s_waitcnt vmcnt(6) lgkmcnt(0)" ::: "memory");
    BAR();

    for (int c = 0; c < 64; ++c) {
        const _Float16* lb = lds + (c & 1) * 8192;
        __builtin_amdgcn_s_setprio(1);
#pragma unroll
        for (int ks = 0; ks < 2; ++ks) {
            half8 fa[2], fb[2];
#pragma unroll
            for (int i = 0; i < 2; ++i) {
                fa[i] = *(const half8*)(lb + ((((wy * 2 + i) << 1) + ks) << 9) + ro);
                fb[i] = *(const half8*)(lb + 4096 + ((((wx * 2 + i) << 1) + ks) << 9) + ro);
            }
#pragma unroll
            for (int j = 0; j < 2; ++j)
#pragma unroll
                for (int i = 0; i < 2; ++i)
                    acc[i][j] = __builtin_amdgcn_mfma_f32_32x32x16_f16(fa[i], fb[j], acc[i][j], 0, 0, 0);
        }
        __builtin_amdgcn_s_setprio(0);
        if (c == 63) break;
        BAR();                           // readers of buf[c&1] done
        if (c < 61) {
            stageB(c + 2, c & 1);        // B(c+2) flies across barriers
            writeA(c & 1);               // A(c+2); implicit wait drains loadA(c+2)
            loadA(c + 3);                // A regs for next chunk's writeA
            asm volatile("s_waitcnt vmcnt(6) lgkmcnt(0)" ::: "memory");
        } else if (c == 61) {
            stageB(63, 1);
            writeA(1);                   // A(63) from loadA(63) (issued at c=60)
            asm volatile("s_waitcnt vmcnt(2) lgkmcnt(0)" ::: "memory");
        } else {                         // c == 62: drain stageB(63)
            asm volatile("s_waitcnt vmcnt(0) lgkmcnt(0)" ::: "memory");
        }
        BAR();                           // buf[(c+1)&1] published
    }

    const float beta = beta_p[0];
#pragma unroll
    for (int i = 0; i < 2; ++i) {
#pragma unroll
        for (int reg = 0; reg < 16; ++reg) {
            const int rr = (reg & 3) + 8 * (reg >> 2) + 4 * lh;
            const int b = b0 + wy * 64 + i * 32 + rr;
            const float cb = beta * (1.0f / 512.0f) * sqrtf(na2[b]);
            float s = 0.f;
#pragma unroll
            for (int j = 0; j < 2; ++j) {
                const int m = m0 + wx * 64 + j * 32 + ln;
                const size_t po = ((size_t)(b >> 5) * 32 + (m >> 4)) * 512
                                + (((size_t)(m >> 3) & 1) << 8) + ((b & 31) << 3) + (m & 7);
                const size_t yi = (size_t)b * Msz + m;
                float vold = (float)vh[po];
                float val = y[yi] - beta * acc[i][j][reg] + cb * vold;
                vh[po] = (_Float16)val;
                s = fmaf(val, val, s);
            }
            s += __shfl_down(s, 16, 32);
            s += __shfl_down(s, 8, 32);
            s += __shfl_down(s, 4, 32);
            s += __shfl_down(s, 2, 32);
            s += __shfl_down(s, 1, 32);
            if (ln == 0) atomicAdd(&t2[b], s);
        }
    }
}

extern "C" void kernel_launch(void* const* d_in, const int* in_sizes, int n_in,
                              void* d_out, int out_size, void* d_ws, size_t ws_size,
                              hipStream_t stream) {
    (void)in_sizes; (void)n_in; (void)out_size; (void)ws_size;
    const float* batch   = (const float*)d_in[0];   // [B, M]
    const float* D       = (const float*)d_in[1];   // [M, N]
    const float* gamma_p = (const float*)d_in[2];   // scalar
    const float* beta_p  = (const float*)d_in[3];   // scalar

    uint* alphaP = (uint*)d_out;    // packed hi/lo per element (plain layout); fp32 after final iter

    // workspace (~22 MB)
    _Float16* vh   = (_Float16*)d_ws;               // [B*M] permuted, single plane
    _Float16* Dph  = vh + (size_t)Bsz * Msz;        // [M*N] permuted (gemm2 B), f16
    _Float16* Dtph = Dph + (size_t)Msz * Nsz;       // [N*M] permuted (gemm1 B), f16
    float*    t2s  = (float*)(Dtph + (size_t)Msz * Nsz);   // [10][Bsz] sum v^2
    float*    na2s = t2s + 10 * Bsz;                        // [10][Bsz] sum alpha^2

    // zero t2 slabs 1..9 + na2 slabs 0..9 (contiguous 19*Bsz floats)
    zero_kernel<<<19 * Bsz / 1024, 256, 0, stream>>>((float4*)(t2s + Bsz));
    convD_kernel<<<dim3(Nsz / 64, Msz / 64), 256, 0, stream>>>(D, Dph, Dtph);
    init_kernel<<<Bsz / 4, 256, 0, stream>>>(batch, vh, t2s);   // writes t2 slab 0

    for (int it = 0; it < 10; ++it) {
        gemm1_kernel<<<2048, 256, 0, stream>>>(vh, Dtph,
                                               t2s + (size_t)it * Bsz,
                                               alphaP,
                                               na2s + (size_t)it * Bsz,
                                               beta_p, gamma_p,
                                               it == 0 ? 1 : 0, it == 9 ? 1 : 0);
        if (it < 9) {   // last iteration's new_v is unused by the reference output
            gemm2_kernel<<<512, 256, 0, stream>>>(alphaP, Dph,
                                                  na2s + (size_t)it * Bsz,
                                                  batch, vh,
                                                  t2s + (size_t)(it + 1) * Bsz,
                                                  beta_p);
        }
    }
}